// Round 16
// baseline (282.095 us; speedup 1.0000x reference)
//
#include <hip/hip_runtime.h>
#include <hip/hip_bf16.h>
#include <math.h>

#define N_NODES 50000
#define N_EDGES 800000
#define NB_SCAN ((N_NODES + 255) / 256)   // 196

typedef _Float16 half8 __attribute__((ext_vector_type(8)));
typedef _Float16 half4 __attribute__((ext_vector_type(4)));
typedef float f32x4 __attribute__((ext_vector_type(4)));

// fast ELU: hardware v_exp_f32; abs err ~1e-7 << tolerance
__device__ __forceinline__ float elu_f(float x) { return x > 0.f ? x : __expf(x) - 1.f; }
__device__ __forceinline__ float edge_score(float2 o) {
    return 1.f / (fabsf(o.x) + fabsf(o.y) + 0.001f);   // > 0 always
}

// ======================= CSR build =========================================
__global__ __launch_bounds__(256)
void k_deg(const int* __restrict__ dst, int* __restrict__ deg) {
    int e = blockIdx.x * 256 + threadIdx.x;
    if (e >= N_EDGES) return;
    atomicAdd(&deg[dst[e]], 1);
}

__global__ __launch_bounds__(256)
void k_bsum(const int* __restrict__ deg, int* __restrict__ bsum) {
    int i = blockIdx.x * 256 + threadIdx.x;
    int v = (i < N_NODES) ? deg[i] : 0;
    #pragma unroll
    for (int d = 32; d; d >>= 1) v += __shfl_xor(v, d);
    __shared__ int ws[4];
    if ((threadIdx.x & 63) == 0) ws[threadIdx.x >> 6] = v;
    __syncthreads();
    if (threadIdx.x == 0) bsum[blockIdx.x] = ws[0] + ws[1] + ws[2] + ws[3];
}

__global__ __launch_bounds__(256)
void k_bscan(const int* __restrict__ bsum, int* __restrict__ bpre, int* __restrict__ rs) {
    const int t = threadIdx.x, lane = t & 63, wv = t >> 6;
    int v = (t < NB_SCAN) ? bsum[t] : 0;
    int inc = v;
    #pragma unroll
    for (int d = 1; d < 64; d <<= 1) { int u = __shfl_up(inc, d); if (lane >= d) inc += u; }
    __shared__ int wtot[4];
    if (lane == 63) wtot[wv] = inc;
    __syncthreads();
    int add = 0;
    for (int w = 0; w < wv; ++w) add += wtot[w];
    if (t < NB_SCAN) bpre[t] = inc + add - v;
    if (t == 0) rs[N_NODES] = N_EDGES;
}

__global__ __launch_bounds__(256)
void k_wr(const int* __restrict__ deg, const int* __restrict__ bpre,
          int* __restrict__ rs, int* __restrict__ cur) {
    const int i = blockIdx.x * 256 + threadIdx.x;
    const int lane = threadIdx.x & 63, wv = threadIdx.x >> 6;
    int v = (i < N_NODES) ? deg[i] : 0;
    int inc = v;
    #pragma unroll
    for (int d = 1; d < 64; d <<= 1) { int u = __shfl_up(inc, d); if (lane >= d) inc += u; }
    __shared__ int wtot[4];
    if (lane == 63) wtot[wv] = inc;
    __syncthreads();
    int add = bpre[blockIdx.x];
    for (int w = 0; w < wv; ++w) add += wtot[w];
    if (i < N_NODES) { int excl = inc - v + add; rs[i] = excl; cur[i] = excl; }
}

// CSR fill: emit eid_csr (slot -> edge), src_csr, score_csr.
__global__ __launch_bounds__(256)
void k_fill(const int* __restrict__ dst, const int* __restrict__ src,
            const float* __restrict__ off2, int* __restrict__ cur,
            int* __restrict__ eid_csr, int* __restrict__ src_csr,
            float* __restrict__ score_csr) {
    int e = blockIdx.x * 256 + threadIdx.x;
    if (e >= N_EDGES) return;
    int p = atomicAdd(&cur[dst[e]], 1);
    eid_csr[p] = e;
    src_csr[p] = src[e];
    score_csr[p] = edge_score(((const float2*)off2)[e]);
}

// ======================= weight split (node MLP + kW2) — one kernel =========
// node: L0 sW1 K=64 @0 | L1 sW2 K=128 @8192 | L2 mW1 K=192 @24576
//       L3 mW2 K=128 @49152 | L4 mW3 K=128 @65536 | L5 mW4 K=128 @81920
#define WTOT 98304
#define KW2TOT 8192
__global__ __launch_bounds__(256)
void k_wsplit(const float* __restrict__ sW1, const float* __restrict__ sW2,
              const float* __restrict__ mW1, const float* __restrict__ mW2,
              const float* __restrict__ mW3, const float* __restrict__ mW4,
              const float* __restrict__ kW2,
              _Float16* __restrict__ wsH, _Float16* __restrict__ wsL,
              _Float16* __restrict__ wkH, _Float16* __restrict__ wkL) {
    int idx = blockIdx.x * 256 + threadIdx.x;
    if (idx < WTOT) {
        const float* W; int base, K;
        if      (idx < 8192)  { W = sW1; base = 0;     K = 64;  }
        else if (idx < 24576) { W = sW2; base = 8192;  K = 128; }
        else if (idx < 49152) { W = mW1; base = 24576; K = 192; }
        else if (idx < 65536) { W = mW2; base = 49152; K = 128; }
        else if (idx < 81920) { W = mW3; base = 65536; K = 128; }
        else                  { W = mW4; base = 81920; K = 128; }
        int local = idx - base;
        int k = local >> 7, col = local & 127;
        int nt = col >> 4, colg = col & 15;
        int kt = k >> 5, lq = (k >> 3) & 3, i = k & 7;
        int fi = base + ((nt * (K >> 5) + kt) * 4 + lq) * 128 + colg * 8 + i;
        float w = W[k * 128 + col];
        _Float16 h = (_Float16)w;
        wsH[fi] = h;
        wsL[fi] = (_Float16)(w - (float)h);
    } else if (idx < WTOT + KW2TOT) {
        int x = idx - WTOT;
        int i = x & 7, colg = (x >> 3) & 15;
        int lq = (x >> 7) & 3, kt = (x >> 9) & 3, jt = x >> 11;
        int k = kt * 32 + lq * 8 + i;
        int j = jt * 16 + colg;
        float w = kW2[k * 64 + j];
        _Float16 h = (_Float16)w;
        wkH[x] = h;
        wkL[x] = (_Float16)(w - (float)h);
    }
}

// ======================= per-edge kernel-weight GEMM (CSR-ordered) ==========
// Round-15 form + ONE change: wk fragments staged in LDS once per block
// (32 KB, shared by 4 waves) — fragment reads become fixed-latency
// ds_read_b128 (2-way bank aliasing = free) instead of L1/L2 global loads
// that the kernel's own streaming stores keep thrashing.
__global__ __launch_bounds__(256)
void k_kw(const float* __restrict__ off2, const int* __restrict__ eid_csr,
          const float* __restrict__ kW1, const float* __restrict__ kb1,
          const _Float16* __restrict__ wkH, const _Float16* __restrict__ wkL,
          const float* __restrict__ kb2, _Float16* __restrict__ kwbuf) {
    __shared__ _Float16 swkH[KW2TOT];   // 16 KB
    __shared__ _Float16 swkL[KW2TOT];   // 16 KB
    const int t = threadIdx.x;
    const int lane = t & 63, wv = t >> 6;
    const int pb = blockIdx.x * 256 + wv * 64;   // CSR slot base for this wave
    const int colg = lane & 15, lq = lane >> 4;

    // ---- stage wk fragments -> LDS (each thread 64 halves = 4x half8) ----
    #pragma unroll
    for (int q = 0; q < 4; ++q) {
        int idx = (q * 256 + t) * 8;
        *(half8*)&swkH[idx] = *(const half8*)&wkH[idx];
        *(half8*)&swkL[idx] = *(const half8*)&wkL[idx];
    }

    float2 o[4];
    #pragma unroll
    for (int et = 0; et < 4; ++et)
        o[et] = ((const float2*)off2)[eid_csr[pb + et * 16 + colg]];

    __syncthreads();

    f32x4 c[4][4];   // [et][jt]
    #pragma unroll
    for (int et = 0; et < 4; ++et)
        #pragma unroll
        for (int jt = 0; jt < 4; ++jt) c[et][jt] = (f32x4){0.f, 0.f, 0.f, 0.f};

    #pragma unroll
    for (int kt = 0; kt < 4; ++kt) {
        const int k0 = kt * 32 + lq * 8;
        float4 a0 = *(const float4*)&kW1[k0];
        float4 a1 = *(const float4*)&kW1[k0 + 4];
        float4 b0 = *(const float4*)&kW1[128 + k0];
        float4 b1 = *(const float4*)&kW1[128 + k0 + 4];
        float4 c0 = *(const float4*)&kb1[k0];
        float4 c1 = *(const float4*)&kb1[k0 + 4];
        const float wa[8] = {a0.x, a0.y, a0.z, a0.w, a1.x, a1.y, a1.z, a1.w};
        const float wb[8] = {b0.x, b0.y, b0.z, b0.w, b1.x, b1.y, b1.z, b1.w};
        const float bb[8] = {c0.x, c0.y, c0.z, c0.w, c1.x, c1.y, c1.z, c1.w};

        half8 Bh[4], Bl[4];
        #pragma unroll
        for (int et = 0; et < 4; ++et) {
            #pragma unroll
            for (int i = 0; i < 8; ++i) {
                float h = elu_f(fmaf(o[et].y, wb[i], fmaf(o[et].x, wa[i], bb[i])));
                _Float16 hh = (_Float16)h;
                Bh[et][i] = hh;
                Bl[et][i] = (_Float16)(h - (float)hh);
            }
        }
        #pragma unroll
        for (int jt = 0; jt < 4; ++jt) {
            int fo = ((jt * 4 + kt) * 4 + lq) * 128 + colg * 8;
            half8 Ah = *(const half8*)&swkH[fo];
            half8 Al = *(const half8*)&swkL[fo];
            #pragma unroll
            for (int et = 0; et < 4; ++et) {
                c[et][jt] = __builtin_amdgcn_mfma_f32_16x16x32_f16(Ah, Bh[et], c[et][jt], 0, 0, 0);
                c[et][jt] = __builtin_amdgcn_mfma_f32_16x16x32_f16(Ah, Bl[et], c[et][jt], 0, 0, 0);
                c[et][jt] = __builtin_amdgcn_mfma_f32_16x16x32_f16(Al, Bh[et], c[et][jt], 0, 0, 0);
            }
        }
    }

    // epilogue: slot p = pb + et*16+colg (sequential rows), 8B stores
    #pragma unroll
    for (int jt = 0; jt < 4; ++jt) {
        const int j0 = jt * 16 + lq * 4;
        float4 bv = *(const float4*)&kb2[j0];
        const float bias4[4] = {bv.x, bv.y, bv.z, bv.w};
        #pragma unroll
        for (int et = 0; et < 4; ++et) {
            const int p = pb + et * 16 + colg;
            half4 v;
            #pragma unroll
            for (int r = 0; r < 4; ++r) v[r] = (_Float16)(c[et][jt][r] + bias4[r]);
            *(half4*)&kwbuf[(size_t)p * 64 + j0] = v;
        }
    }
}

// ======================= per-node softmax + gather-aggregate ================
__global__ __launch_bounds__(256)
void k_agg(const float* __restrict__ score_csr, const int* __restrict__ src_csr,
           const int* __restrict__ rs, const float* __restrict__ feat,
           const _Float16* __restrict__ kwbuf, float* __restrict__ agg) {
    const int lane = threadIdx.x & 63;
    const int wav  = threadIdx.x >> 6;
    const int gw   = blockIdx.x * 4 + wav;
    const int nw   = gridDim.x * 4;

    for (int n = gw; n < N_NODES; n += nw) {
        const int p0 = rs[n], p1 = rs[n + 1];
        if (p0 == p1) { agg[(size_t)n * 64 + lane] = 0.f; continue; }

        float mx = 0.f;
        for (int p = p0 + lane; p < p1; p += 64) mx = fmaxf(mx, score_csr[p]);
        #pragma unroll
        for (int d = 32; d; d >>= 1) mx = fmaxf(mx, __shfl_xor(mx, d));

        float sm = 0.f;
        for (int p = p0 + lane; p < p1; p += 64) sm += __expf(score_csr[p] - mx);
        #pragma unroll
        for (int d = 32; d; d >>= 1) sm += __shfl_xor(sm, d);
        const float dinv = 1.f / sm;

        float a0 = 0.f, a1 = 0.f, a2 = 0.f, a3 = 0.f;
        int p = p0;
        for (; p + 4 <= p1; p += 4) {
            float w0 = __expf(score_csr[p]     - mx) * dinv;
            float w1 = __expf(score_csr[p + 1] - mx) * dinv;
            float w2 = __expf(score_csr[p + 2] - mx) * dinv;
            float w3 = __expf(score_csr[p + 3] - mx) * dinv;
            const int s0 = src_csr[p], s1 = src_csr[p + 1];
            const int s2 = src_csr[p + 2], s3 = src_csr[p + 3];
            float f0 = feat[(size_t)s0 * 64 + lane];
            float f1 = feat[(size_t)s1 * 64 + lane];
            float f2 = feat[(size_t)s2 * 64 + lane];
            float f3 = feat[(size_t)s3 * 64 + lane];
            float k0 = (float)kwbuf[(size_t)(p)     * 64 + lane];
            float k1 = (float)kwbuf[(size_t)(p + 1) * 64 + lane];
            float k2 = (float)kwbuf[(size_t)(p + 2) * 64 + lane];
            float k3 = (float)kwbuf[(size_t)(p + 3) * 64 + lane];
            a0 = fmaf(f0 * w0, k0, a0);
            a1 = fmaf(f1 * w1, k1, a1);
            a2 = fmaf(f2 * w2, k2, a2);
            a3 = fmaf(f3 * w3, k3, a3);
        }
        for (; p < p1; ++p) {
            float wgt = __expf(score_csr[p] - mx) * dinv;
            float f = feat[(size_t)src_csr[p] * 64 + lane];
            float kv = (float)kwbuf[(size_t)p * 64 + lane];
            a0 = fmaf(f * wgt, kv, a0);
        }
        agg[(size_t)n * 64 + lane] = (a0 + a1) + (a2 + a3);
    }
}

// ======================= fused node pipeline (MFMA) =========================
// X LDS is 64x128 hi/lo (32 KB total). agg for head-L1 staged in registers.
__device__ __forceinline__
void mm64(const char* XH, const char* XL, const _Float16* __restrict__ WH,
          const _Float16* __restrict__ WL, int K, int lane, int wv, f32x4 c[4][2]) {
    const int colg = lane & 15, lq = lane >> 4;
    #pragma unroll
    for (int m = 0; m < 4; ++m)
        #pragma unroll
        for (int j = 0; j < 2; ++j) c[m][j] = (f32x4){0.f, 0.f, 0.f, 0.f};
    const int KT = K >> 5;
    for (int kt = 0; kt < KT; ++kt) {
        half8 Bh[2], Bl[2], Ah[4], Al[4];
        #pragma unroll
        for (int j = 0; j < 2; ++j) {
            int fo = ((((wv * 2 + j) * KT + kt) * 4 + lq) * 128) + colg * 8;
            Bh[j] = *(const half8*)&WH[fo];
            Bl[j] = *(const half8*)&WL[fo];
        }
        #pragma unroll
        for (int m = 0; m < 4; ++m) {
            int row = m * 16 + colg;
            int byte = ((row * K + kt * 32 + lq * 8) * 2) ^ ((row & 7) << 4);
            Ah[m] = *(const half8*)(XH + byte);
            Al[m] = *(const half8*)(XL + byte);
        }
        #pragma unroll
        for (int m = 0; m < 4; ++m)
            #pragma unroll
            for (int j = 0; j < 2; ++j) {
                c[m][j] = __builtin_amdgcn_mfma_f32_16x16x32_f16(Ah[m], Bh[j], c[m][j], 0, 0, 0);
                c[m][j] = __builtin_amdgcn_mfma_f32_16x16x32_f16(Ah[m], Bl[j], c[m][j], 0, 0, 0);
                c[m][j] = __builtin_amdgcn_mfma_f32_16x16x32_f16(Al[m], Bh[j], c[m][j], 0, 0, 0);
            }
    }
}

// head-L1: K=192; kt 0,1 (agg) from registers, kt 2..5 (selfb) from LDS.
__device__ __forceinline__
void mm64_h1(const half8 aggH[4][2], const half8 aggL[4][2],
             const char* XH, const char* XL,
             const _Float16* __restrict__ WH, const _Float16* __restrict__ WL,
             int lane, int wv, f32x4 c[4][2]) {
    const int colg = lane & 15, lq = lane >> 4;
    #pragma unroll
    for (int m = 0; m < 4; ++m)
        #pragma unroll
        for (int j = 0; j < 2; ++j) c[m][j] = (f32x4){0.f, 0.f, 0.f, 0.f};
    #pragma unroll
    for (int kt = 0; kt < 6; ++kt) {
        half8 Bh[2], Bl[2], Ah[4], Al[4];
        #pragma unroll
        for (int j = 0; j < 2; ++j) {
            int fo = ((((wv * 2 + j) * 6 + kt) * 4 + lq) * 128) + colg * 8;
            Bh[j] = *(const half8*)&WH[fo];
            Bl[j] = *(const half8*)&WL[fo];
        }
        if (kt < 2) {
            #pragma unroll
            for (int m = 0; m < 4; ++m) { Ah[m] = aggH[m][kt]; Al[m] = aggL[m][kt]; }
        } else {
            #pragma unroll
            for (int m = 0; m < 4; ++m) {
                int row = m * 16 + colg;
                int byte = ((row * 128 + (kt - 2) * 32 + lq * 8) * 2) ^ ((row & 7) << 4);
                Ah[m] = *(const half8*)(XH + byte);
                Al[m] = *(const half8*)(XL + byte);
            }
        }
        #pragma unroll
        for (int m = 0; m < 4; ++m)
            #pragma unroll
            for (int j = 0; j < 2; ++j) {
                c[m][j] = __builtin_amdgcn_mfma_f32_16x16x32_f16(Ah[m], Bh[j], c[m][j], 0, 0, 0);
                c[m][j] = __builtin_amdgcn_mfma_f32_16x16x32_f16(Ah[m], Bl[j], c[m][j], 0, 0, 0);
                c[m][j] = __builtin_amdgcn_mfma_f32_16x16x32_f16(Al[m], Bh[j], c[m][j], 0, 0, 0);
            }
    }
}

__device__ __forceinline__
void epi_lds(char* XH, char* XL, int lane, int wv,
             f32x4 c[4][2], const float* __restrict__ bias, bool do_elu) {
    const int colg = lane & 15, lq = lane >> 4;
    float bj[2] = { bias[wv * 32 + colg], bias[wv * 32 + 16 + colg] };
    #pragma unroll
    for (int m = 0; m < 4; ++m)
        #pragma unroll
        for (int j = 0; j < 2; ++j) {
            int col = wv * 32 + j * 16 + colg;
            #pragma unroll
            for (int r = 0; r < 4; ++r) {
                int row = m * 16 + lq * 4 + r;
                float v = c[m][j][r] + bj[j];
                if (do_elu) v = elu_f(v);
                _Float16 h = (_Float16)v;
                int byte = ((row * 128 + col) * 2) ^ ((row & 7) << 4);
                *(_Float16*)(XH + byte) = h;
                *(_Float16*)(XL + byte) = (_Float16)(v - (float)h);
            }
        }
}

__global__ __launch_bounds__(256)
void k_node(const float* __restrict__ feat, const float* __restrict__ agg,
            const _Float16* __restrict__ wsH, const _Float16* __restrict__ wsL,
            const float* __restrict__ sb1, const float* __restrict__ sb2,
            const float* __restrict__ mb1, const float* __restrict__ mb2,
            const float* __restrict__ mb3, const float* __restrict__ mb4,
            float* __restrict__ out) {
    __shared__ _Float16 XH[64 * 128];   // 16 KB
    __shared__ _Float16 XL[64 * 128];   // 16 KB
    const int t = threadIdx.x;
    const int lane = t & 63, wv = t >> 6;
    const int colg = lane & 15, lq = lane >> 4;
    const int row0 = blockIdx.x * 64;
    f32x4 c[4][2];

    // ---- stage feat[64][64] -> X (K=64 swizzled layout) ----
    {
        int r = t >> 2, c4 = (t & 3) * 4;
        #pragma unroll
        for (int q = 0; q < 4; ++q) {
            int col = (c4 + q) * 4;
            float4 v = make_float4(0.f, 0.f, 0.f, 0.f);
            if (row0 + r < N_NODES) v = *(const float4*)&feat[(size_t)(row0 + r) * 64 + col];
            _Float16 h4h[4], h4l[4];
            float vv[4] = {v.x, v.y, v.z, v.w};
            #pragma unroll
            for (int i = 0; i < 4; ++i) {
                _Float16 h = (_Float16)vv[i];
                h4h[i] = h; h4l[i] = (_Float16)(vv[i] - (float)h);
            }
            int byte = ((r * 64 + col) * 2) ^ ((r & 7) << 4);
            *(ulong1*)((char*)XH + byte) = *(ulong1*)h4h;
            *(ulong1*)((char*)XL + byte) = *(ulong1*)h4l;
        }
    }
    __syncthreads();

    // ---- self L1: K=64, ELU ----
    mm64((const char*)XH, (const char*)XL, wsH + 0, wsL + 0, 64, lane, wv, c);
    __syncthreads();
    epi_lds((char*)XH, (char*)XL, lane, wv, c, sb1, true);
    __syncthreads();

    // ---- self L2: K=128, no ELU -> selfb stays in X ----
    mm64((const char*)XH, (const char*)XL, wsH + 8192, wsL + 8192, 128, lane, wv, c);

    // ---- stage agg -> head-L1 A-fragment registers ----
    half8 aggH[4][2], aggL[4][2];
    #pragma unroll
    for (int m = 0; m < 4; ++m) {
        int row = row0 + m * 16 + colg;
        #pragma unroll
        for (int kt = 0; kt < 2; ++kt) {
            int k0 = kt * 32 + lq * 8;
            float4 v0 = make_float4(0.f, 0.f, 0.f, 0.f), v1 = v0;
            if (row < N_NODES) {
                v0 = *(const float4*)&agg[(size_t)row * 64 + k0];
                v1 = *(const float4*)&agg[(size_t)row * 64 + k0 + 4];
            }
            float vv[8] = {v0.x, v0.y, v0.z, v0.w, v1.x, v1.y, v1.z, v1.w};
            #pragma unroll
            for (int i = 0; i < 8; ++i) {
                _Float16 h = (_Float16)vv[i];
                aggH[m][kt][i] = h;
                aggL[m][kt][i] = (_Float16)(vv[i] - (float)h);
            }
        }
    }
    __syncthreads();
    epi_lds((char*)XH, (char*)XL, lane, wv, c, sb2, false);
    __syncthreads();

    // ---- head L1: K=192 (regs + LDS), ELU ----
    mm64_h1(aggH, aggL, (const char*)XH, (const char*)XL,
            wsH + 24576, wsL + 24576, lane, wv, c);
    __syncthreads();
    epi_lds((char*)XH, (char*)XL, lane, wv, c, mb1, true);
    __syncthreads();

    // ---- head L2: K=128, ELU ----
    mm64((const char*)XH, (const char*)XL, wsH + 49152, wsL + 49152, 128, lane, wv, c);
    __syncthreads();
    epi_lds((char*)XH, (char*)XL, lane, wv, c, mb2, true);
    __syncthreads();

    // ---- head L3: K=128, ELU ----
    mm64((const char*)XH, (const char*)XL, wsH + 65536, wsL + 65536, 128, lane, wv, c);
    __syncthreads();
    epi_lds((char*)XH, (char*)XL, lane, wv, c, mb3, true);
    __syncthreads();

    // ---- head L4: K=128 -> global out ----
    mm64((const char*)XH, (const char*)XL, wsH + 81920, wsL + 81920, 128, lane, wv, c);
    {
        float bj[2] = { mb4[wv * 32 + colg], mb4[wv * 32 + 16 + colg] };
        #pragma unroll
        for (int m = 0; m < 4; ++m)
            #pragma unroll
            for (int j = 0; j < 2; ++j) {
                int col = wv * 32 + j * 16 + colg;
                #pragma unroll
                for (int r = 0; r < 4; ++r) {
                    int row = row0 + m * 16 + lq * 4 + r;
                    if (row < N_NODES)
                        out[(size_t)row * 128 + col] = c[m][j][r] + bj[j];
                }
            }
    }
}

// ============================================================================
extern "C" void kernel_launch(void* const* d_in, const int* in_sizes, int n_in,
                              void* d_out, int out_size, void* d_ws, size_t ws_size,
                              hipStream_t stream) {
    (void)in_sizes; (void)n_in; (void)out_size; (void)ws_size;
    const float* feat = (const float*)d_in[0];
    const float* off2 = (const float*)d_in[1];
    const int*   src  = (const int*)d_in[2];
    const int*   dst  = (const int*)d_in[3];
    const float* kW1  = (const float*)d_in[4];
    const float* kb1  = (const float*)d_in[5];
    const float* kW2  = (const float*)d_in[6];
    const float* kb2  = (const float*)d_in[7];
    const float* sW1  = (const float*)d_in[8];
    const float* sb1  = (const float*)d_in[9];
    const float* sW2  = (const float*)d_in[10];
    const float* sb2  = (const float*)d_in[11];
    const float* mW1  = (const float*)d_in[12];
    const float* mb1  = (const float*)d_in[13];
    const float* mW2  = (const float*)d_in[14];
    const float* mb2  = (const float*)d_in[15];
    const float* mW3  = (const float*)d_in[16];
    const float* mb3  = (const float*)d_in[17];
    const float* mW4  = (const float*)d_in[18];
    const float* mb4  = (const float*)d_in[19];

    char* ws = (char*)d_ws;
    size_t off = 0;
    auto alloc = [&](size_t bytes) -> void* {
        void* p = ws + off;
        off += (bytes + 255) & ~(size_t)255;
        return p;
    };
    int*   deg    = (int*)alloc((size_t)N_NODES * 4);
    int*   rs     = (int*)alloc((size_t)(N_NODES + 8) * 4);
    int*   cur    = (int*)alloc((size_t)N_NODES * 4);
    int*   bsum   = (int*)alloc((size_t)NB_SCAN * 4);
    int*   bpre   = (int*)alloc((size_t)NB_SCAN * 4);
    int*   eidc   = (int*)alloc((size_t)N_EDGES * 4);
    int*   srcc   = (int*)alloc((size_t)N_EDGES * 4);
    float* scorec = (float*)alloc((size_t)N_EDGES * 4);
    float* agg    = (float*)alloc((size_t)N_NODES * 64 * 4);
    _Float16* wsH = (_Float16*)alloc((size_t)WTOT * 2);
    _Float16* wsL = (_Float16*)alloc((size_t)WTOT * 2);
    _Float16* wkH = (_Float16*)alloc((size_t)KW2TOT * 2);
    _Float16* wkL = (_Float16*)alloc((size_t)KW2TOT * 2);
    _Float16* kwbuf = (_Float16*)alloc((size_t)N_EDGES * 64 * 2);

    hipMemsetAsync(deg, 0, (size_t)N_NODES * 4, stream);

    const int EB = (N_EDGES + 255) / 256;   // 3125
    const int GB = (N_NODES + 63) / 64;     // 782

    k_deg   <<<EB, 256, 0, stream>>>(dst, deg);
    k_bsum  <<<NB_SCAN, 256, 0, stream>>>(deg, bsum);
    k_bscan <<<1, 256, 0, stream>>>(bsum, bpre, rs);
    k_wr    <<<NB_SCAN, 256, 0, stream>>>(deg, bpre, rs, cur);
    k_fill  <<<EB, 256, 0, stream>>>(dst, src, off2, cur, eidc, srcc, scorec);
    k_wsplit<<<(WTOT + KW2TOT + 255) / 256, 256, 0, stream>>>(sW1, sW2, mW1, mW2, mW3, mW4,
                                                              kW2, wsH, wsL, wkH, wkL);

    k_kw <<<N_EDGES / 256, 256, 0, stream>>>(off2, eidc, kW1, kb1, wkH, wkL, kb2, kwbuf);
    k_agg<<<2048, 256, 0, stream>>>(scorec, srcc, rs, feat, kwbuf, agg);

    k_node<<<GB, 256, 0, stream>>>(feat, agg, wsH, wsL, sb1, sb2, mb1, mb2, mb3, mb4,
                                   (float*)d_out);
}

// Round 17
// 275.336 us; speedup vs baseline: 1.0245x; 1.0245x over previous
//
#include <hip/hip_runtime.h>
#include <hip/hip_bf16.h>
#include <math.h>

#define N_NODES 50000
#define N_EDGES 800000
#define NB_SCAN ((N_NODES + 255) / 256)   // 196

typedef _Float16 half8 __attribute__((ext_vector_type(8)));
typedef _Float16 half4 __attribute__((ext_vector_type(4)));
typedef float f32x4 __attribute__((ext_vector_type(4)));

// fast ELU: hardware v_exp_f32; abs err ~1e-7 << tolerance
__device__ __forceinline__ float elu_f(float x) { return x > 0.f ? x : __expf(x) - 1.f; }
__device__ __forceinline__ float edge_score(float2 o) {
    return 1.f / (fabsf(o.x) + fabsf(o.y) + 0.001f);   // > 0 always
}

// ======================= CSR build =========================================
__global__ __launch_bounds__(256)
void k_deg(const int* __restrict__ dst, int* __restrict__ deg) {
    int e = blockIdx.x * 256 + threadIdx.x;
    if (e >= N_EDGES) return;
    atomicAdd(&deg[dst[e]], 1);
}

__global__ __launch_bounds__(256)
void k_bsum(const int* __restrict__ deg, int* __restrict__ bsum) {
    int i = blockIdx.x * 256 + threadIdx.x;
    int v = (i < N_NODES) ? deg[i] : 0;
    #pragma unroll
    for (int d = 32; d; d >>= 1) v += __shfl_xor(v, d);
    __shared__ int ws[4];
    if ((threadIdx.x & 63) == 0) ws[threadIdx.x >> 6] = v;
    __syncthreads();
    if (threadIdx.x == 0) bsum[blockIdx.x] = ws[0] + ws[1] + ws[2] + ws[3];
}

__global__ __launch_bounds__(256)
void k_bscan(const int* __restrict__ bsum, int* __restrict__ bpre, int* __restrict__ rs) {
    const int t = threadIdx.x, lane = t & 63, wv = t >> 6;
    int v = (t < NB_SCAN) ? bsum[t] : 0;
    int inc = v;
    #pragma unroll
    for (int d = 1; d < 64; d <<= 1) { int u = __shfl_up(inc, d); if (lane >= d) inc += u; }
    __shared__ int wtot[4];
    if (lane == 63) wtot[wv] = inc;
    __syncthreads();
    int add = 0;
    for (int w = 0; w < wv; ++w) add += wtot[w];
    if (t < NB_SCAN) bpre[t] = inc + add - v;
    if (t == 0) rs[N_NODES] = N_EDGES;
}

__global__ __launch_bounds__(256)
void k_wr(const int* __restrict__ deg, const int* __restrict__ bpre,
          int* __restrict__ rs, int* __restrict__ cur) {
    const int i = blockIdx.x * 256 + threadIdx.x;
    const int lane = threadIdx.x & 63, wv = threadIdx.x >> 6;
    int v = (i < N_NODES) ? deg[i] : 0;
    int inc = v;
    #pragma unroll
    for (int d = 1; d < 64; d <<= 1) { int u = __shfl_up(inc, d); if (lane >= d) inc += u; }
    __shared__ int wtot[4];
    if (lane == 63) wtot[wv] = inc;
    __syncthreads();
    int add = bpre[blockIdx.x];
    for (int w = 0; w < wv; ++w) add += wtot[w];
    if (i < N_NODES) { int excl = inc - v + add; rs[i] = excl; cur[i] = excl; }
}

// CSR fill: emit eid_csr (slot -> edge), src_csr, score_csr.
__global__ __launch_bounds__(256)
void k_fill(const int* __restrict__ dst, const int* __restrict__ src,
            const float* __restrict__ off2, int* __restrict__ cur,
            int* __restrict__ eid_csr, int* __restrict__ src_csr,
            float* __restrict__ score_csr) {
    int e = blockIdx.x * 256 + threadIdx.x;
    if (e >= N_EDGES) return;
    int p = atomicAdd(&cur[dst[e]], 1);
    eid_csr[p] = e;
    src_csr[p] = src[e];
    score_csr[p] = edge_score(((const float2*)off2)[e]);
}

// ======================= weight split (node MLP + kW2) — one kernel =========
// node: L0 sW1 K=64 @0 | L1 sW2 K=128 @8192 | L2 mW1 K=192 @24576
//       L3 mW2 K=128 @49152 | L4 mW3 K=128 @65536 | L5 mW4 K=128 @81920
#define WTOT 98304
#define KW2TOT 8192
__global__ __launch_bounds__(256)
void k_wsplit(const float* __restrict__ sW1, const float* __restrict__ sW2,
              const float* __restrict__ mW1, const float* __restrict__ mW2,
              const float* __restrict__ mW3, const float* __restrict__ mW4,
              const float* __restrict__ kW2,
              _Float16* __restrict__ wsH, _Float16* __restrict__ wsL,
              _Float16* __restrict__ wkH, _Float16* __restrict__ wkL) {
    int idx = blockIdx.x * 256 + threadIdx.x;
    if (idx < WTOT) {
        const float* W; int base, K;
        if      (idx < 8192)  { W = sW1; base = 0;     K = 64;  }
        else if (idx < 24576) { W = sW2; base = 8192;  K = 128; }
        else if (idx < 49152) { W = mW1; base = 24576; K = 192; }
        else if (idx < 65536) { W = mW2; base = 49152; K = 128; }
        else if (idx < 81920) { W = mW3; base = 65536; K = 128; }
        else                  { W = mW4; base = 81920; K = 128; }
        int local = idx - base;
        int k = local >> 7, col = local & 127;
        int nt = col >> 4, colg = col & 15;
        int kt = k >> 5, lq = (k >> 3) & 3, i = k & 7;
        int fi = base + ((nt * (K >> 5) + kt) * 4 + lq) * 128 + colg * 8 + i;
        float w = W[k * 128 + col];
        _Float16 h = (_Float16)w;
        wsH[fi] = h;
        wsL[fi] = (_Float16)(w - (float)h);
    } else if (idx < WTOT + KW2TOT) {
        int x = idx - WTOT;
        int i = x & 7, colg = (x >> 3) & 15;
        int lq = (x >> 7) & 3, kt = (x >> 9) & 3, jt = x >> 11;
        int k = kt * 32 + lq * 8 + i;
        int j = jt * 16 + colg;
        float w = kW2[k * 64 + j];
        _Float16 h = (_Float16)w;
        wkH[x] = h;
        wkL[x] = (_Float16)(w - (float)h);
    }
}

// ======================= per-edge kernel-weight GEMM (CSR-ordered) ==========
// Round-15 form + ONE change: epilogue stages D-tiles in LDS (swizzled) and
// a cooperative copy emits fully-coalesced 16B/lane streaming stores —
// replaces the 8B/lane, 32B-granule scattered store pattern that pinned the
// write path at ~1.25 TB/s across all prior variants.
__global__ __launch_bounds__(256)
void k_kw(const float* __restrict__ off2, const int* __restrict__ eid_csr,
          const float* __restrict__ kW1, const float* __restrict__ kb1,
          const _Float16* __restrict__ wkH, const _Float16* __restrict__ wkL,
          const float* __restrict__ kb2, _Float16* __restrict__ kwbuf) {
    __shared__ _Float16 stg[256 * 64];   // 32 KB: 256 slots x 128 B
    const int t = threadIdx.x;
    const int lane = t & 63, wv = t >> 6;
    const int pb = blockIdx.x * 256 + wv * 64;   // CSR slot base for this wave
    const int colg = lane & 15, lq = lane >> 4;

    float2 o[4];
    #pragma unroll
    for (int et = 0; et < 4; ++et)
        o[et] = ((const float2*)off2)[eid_csr[pb + et * 16 + colg]];

    f32x4 c[4][4];   // [et][jt]
    #pragma unroll
    for (int et = 0; et < 4; ++et)
        #pragma unroll
        for (int jt = 0; jt < 4; ++jt) c[et][jt] = (f32x4){0.f, 0.f, 0.f, 0.f};

    #pragma unroll
    for (int kt = 0; kt < 4; ++kt) {
        const int k0 = kt * 32 + lq * 8;
        float4 a0 = *(const float4*)&kW1[k0];
        float4 a1 = *(const float4*)&kW1[k0 + 4];
        float4 b0 = *(const float4*)&kW1[128 + k0];
        float4 b1 = *(const float4*)&kW1[128 + k0 + 4];
        float4 c0 = *(const float4*)&kb1[k0];
        float4 c1 = *(const float4*)&kb1[k0 + 4];
        const float wa[8] = {a0.x, a0.y, a0.z, a0.w, a1.x, a1.y, a1.z, a1.w};
        const float wb[8] = {b0.x, b0.y, b0.z, b0.w, b1.x, b1.y, b1.z, b1.w};
        const float bb[8] = {c0.x, c0.y, c0.z, c0.w, c1.x, c1.y, c1.z, c1.w};

        half8 Bh[4], Bl[4];
        #pragma unroll
        for (int et = 0; et < 4; ++et) {
            #pragma unroll
            for (int i = 0; i < 8; ++i) {
                float h = elu_f(fmaf(o[et].y, wb[i], fmaf(o[et].x, wa[i], bb[i])));
                _Float16 hh = (_Float16)h;
                Bh[et][i] = hh;
                Bl[et][i] = (_Float16)(h - (float)hh);
            }
        }
        #pragma unroll
        for (int jt = 0; jt < 4; ++jt) {
            int fo = ((jt * 4 + kt) * 4 + lq) * 128 + colg * 8;
            half8 Ah = *(const half8*)&wkH[fo];
            half8 Al = *(const half8*)&wkL[fo];
            #pragma unroll
            for (int et = 0; et < 4; ++et) {
                c[et][jt] = __builtin_amdgcn_mfma_f32_16x16x32_f16(Ah, Bh[et], c[et][jt], 0, 0, 0);
                c[et][jt] = __builtin_amdgcn_mfma_f32_16x16x32_f16(Ah, Bl[et], c[et][jt], 0, 0, 0);
                c[et][jt] = __builtin_amdgcn_mfma_f32_16x16x32_f16(Al, Bh[et], c[et][jt], 0, 0, 0);
            }
        }
    }

    // ---- epilogue phase 1: D -> LDS (swizzled 8B stores) ----
    #pragma unroll
    for (int jt = 0; jt < 4; ++jt) {
        const int j0 = jt * 16 + lq * 4;
        float4 bv = *(const float4*)&kb2[j0];
        const float bias4[4] = {bv.x, bv.y, bv.z, bv.w};
        #pragma unroll
        for (int et = 0; et < 4; ++et) {
            const int ls = wv * 64 + et * 16 + colg;   // local slot 0..255
            half4 v;
            #pragma unroll
            for (int r = 0; r < 4; ++r) v[r] = (_Float16)(c[et][jt][r] + bias4[r]);
            int byte = (ls * 128 + j0 * 2) ^ ((ls & 7) << 4);
            *(half4*)((char*)stg + byte) = v;
        }
    }
    __syncthreads();

    // ---- epilogue phase 2: cooperative coalesced copy (16B/lane) ----
    const size_t gbase = (size_t)blockIdx.x * 256 * 64;
    #pragma unroll
    for (int q = 0; q < 8; ++q) {
        int byte = q * 4096 + t * 16;
        int ls = byte >> 7, off = byte & 127;
        int lb = (ls * 128 + off) ^ ((ls & 7) << 4);
        *(half8*)&kwbuf[gbase + (byte >> 1)] = *(const half8*)((const char*)stg + lb);
    }
}

// ======================= per-node softmax + gather-aggregate ================
__global__ __launch_bounds__(256)
void k_agg(const float* __restrict__ score_csr, const int* __restrict__ src_csr,
           const int* __restrict__ rs, const float* __restrict__ feat,
           const _Float16* __restrict__ kwbuf, float* __restrict__ agg) {
    const int lane = threadIdx.x & 63;
    const int wav  = threadIdx.x >> 6;
    const int gw   = blockIdx.x * 4 + wav;
    const int nw   = gridDim.x * 4;

    for (int n = gw; n < N_NODES; n += nw) {
        const int p0 = rs[n], p1 = rs[n + 1];
        if (p0 == p1) { agg[(size_t)n * 64 + lane] = 0.f; continue; }

        float mx = 0.f;
        for (int p = p0 + lane; p < p1; p += 64) mx = fmaxf(mx, score_csr[p]);
        #pragma unroll
        for (int d = 32; d; d >>= 1) mx = fmaxf(mx, __shfl_xor(mx, d));

        float sm = 0.f;
        for (int p = p0 + lane; p < p1; p += 64) sm += __expf(score_csr[p] - mx);
        #pragma unroll
        for (int d = 32; d; d >>= 1) sm += __shfl_xor(sm, d);
        const float dinv = 1.f / sm;

        float a0 = 0.f, a1 = 0.f, a2 = 0.f, a3 = 0.f;
        int p = p0;
        for (; p + 4 <= p1; p += 4) {
            float w0 = __expf(score_csr[p]     - mx) * dinv;
            float w1 = __expf(score_csr[p + 1] - mx) * dinv;
            float w2 = __expf(score_csr[p + 2] - mx) * dinv;
            float w3 = __expf(score_csr[p + 3] - mx) * dinv;
            const int s0 = src_csr[p], s1 = src_csr[p + 1];
            const int s2 = src_csr[p + 2], s3 = src_csr[p + 3];
            float f0 = feat[(size_t)s0 * 64 + lane];
            float f1 = feat[(size_t)s1 * 64 + lane];
            float f2 = feat[(size_t)s2 * 64 + lane];
            float f3 = feat[(size_t)s3 * 64 + lane];
            float k0 = (float)kwbuf[(size_t)(p)     * 64 + lane];
            float k1 = (float)kwbuf[(size_t)(p + 1) * 64 + lane];
            float k2 = (float)kwbuf[(size_t)(p + 2) * 64 + lane];
            float k3 = (float)kwbuf[(size_t)(p + 3) * 64 + lane];
            a0 = fmaf(f0 * w0, k0, a0);
            a1 = fmaf(f1 * w1, k1, a1);
            a2 = fmaf(f2 * w2, k2, a2);
            a3 = fmaf(f3 * w3, k3, a3);
        }
        for (; p < p1; ++p) {
            float wgt = __expf(score_csr[p] - mx) * dinv;
            float f = feat[(size_t)src_csr[p] * 64 + lane];
            float kv = (float)kwbuf[(size_t)p * 64 + lane];
            a0 = fmaf(f * wgt, kv, a0);
        }
        agg[(size_t)n * 64 + lane] = (a0 + a1) + (a2 + a3);
    }
}

// ======================= fused node pipeline (MFMA) =========================
// X LDS is 64x128 hi/lo (32 KB total). agg for head-L1 staged in registers.
__device__ __forceinline__
void mm64(const char* XH, const char* XL, const _Float16* __restrict__ WH,
          const _Float16* __restrict__ WL, int K, int lane, int wv, f32x4 c[4][2]) {
    const int colg = lane & 15, lq = lane >> 4;
    #pragma unroll
    for (int m = 0; m < 4; ++m)
        #pragma unroll
        for (int j = 0; j < 2; ++j) c[m][j] = (f32x4){0.f, 0.f, 0.f, 0.f};
    const int KT = K >> 5;
    for (int kt = 0; kt < KT; ++kt) {
        half8 Bh[2], Bl[2], Ah[4], Al[4];
        #pragma unroll
        for (int j = 0; j < 2; ++j) {
            int fo = ((((wv * 2 + j) * KT + kt) * 4 + lq) * 128) + colg * 8;
            Bh[j] = *(const half8*)&WH[fo];
            Bl[j] = *(const half8*)&WL[fo];
        }
        #pragma unroll
        for (int m = 0; m < 4; ++m) {
            int row = m * 16 + colg;
            int byte = ((row * K + kt * 32 + lq * 8) * 2) ^ ((row & 7) << 4);
            Ah[m] = *(const half8*)(XH + byte);
            Al[m] = *(const half8*)(XL + byte);
        }
        #pragma unroll
        for (int m = 0; m < 4; ++m)
            #pragma unroll
            for (int j = 0; j < 2; ++j) {
                c[m][j] = __builtin_amdgcn_mfma_f32_16x16x32_f16(Ah[m], Bh[j], c[m][j], 0, 0, 0);
                c[m][j] = __builtin_amdgcn_mfma_f32_16x16x32_f16(Ah[m], Bl[j], c[m][j], 0, 0, 0);
                c[m][j] = __builtin_amdgcn_mfma_f32_16x16x32_f16(Al[m], Bh[j], c[m][j], 0, 0, 0);
            }
    }
}

// head-L1: K=192; kt 0,1 (agg) from registers, kt 2..5 (selfb) from LDS.
__device__ __forceinline__
void mm64_h1(const half8 aggH[4][2], const half8 aggL[4][2],
             const char* XH, const char* XL,
             const _Float16* __restrict__ WH, const _Float16* __restrict__ WL,
             int lane, int wv, f32x4 c[4][2]) {
    const int colg = lane & 15, lq = lane >> 4;
    #pragma unroll
    for (int m = 0; m < 4; ++m)
        #pragma unroll
        for (int j = 0; j < 2; ++j) c[m][j] = (f32x4){0.f, 0.f, 0.f, 0.f};
    #pragma unroll
    for (int kt = 0; kt < 6; ++kt) {
        half8 Bh[2], Bl[2], Ah[4], Al[4];
        #pragma unroll
        for (int j = 0; j < 2; ++j) {
            int fo = ((((wv * 2 + j) * 6 + kt) * 4 + lq) * 128) + colg * 8;
            Bh[j] = *(const half8*)&WH[fo];
            Bl[j] = *(const half8*)&WL[fo];
        }
        if (kt < 2) {
            #pragma unroll
            for (int m = 0; m < 4; ++m) { Ah[m] = aggH[m][kt]; Al[m] = aggL[m][kt]; }
        } else {
            #pragma unroll
            for (int m = 0; m < 4; ++m) {
                int row = m * 16 + colg;
                int byte = ((row * 128 + (kt - 2) * 32 + lq * 8) * 2) ^ ((row & 7) << 4);
                Ah[m] = *(const half8*)(XH + byte);
                Al[m] = *(const half8*)(XL + byte);
            }
        }
        #pragma unroll
        for (int m = 0; m < 4; ++m)
            #pragma unroll
            for (int j = 0; j < 2; ++j) {
                c[m][j] = __builtin_amdgcn_mfma_f32_16x16x32_f16(Ah[m], Bh[j], c[m][j], 0, 0, 0);
                c[m][j] = __builtin_amdgcn_mfma_f32_16x16x32_f16(Ah[m], Bl[j], c[m][j], 0, 0, 0);
                c[m][j] = __builtin_amdgcn_mfma_f32_16x16x32_f16(Al[m], Bh[j], c[m][j], 0, 0, 0);
            }
    }
}

__device__ __forceinline__
void epi_lds(char* XH, char* XL, int lane, int wv,
             f32x4 c[4][2], const float* __restrict__ bias, bool do_elu) {
    const int colg = lane & 15, lq = lane >> 4;
    float bj[2] = { bias[wv * 32 + colg], bias[wv * 32 + 16 + colg] };
    #pragma unroll
    for (int m = 0; m < 4; ++m)
        #pragma unroll
        for (int j = 0; j < 2; ++j) {
            int col = wv * 32 + j * 16 + colg;
            #pragma unroll
            for (int r = 0; r < 4; ++r) {
                int row = m * 16 + lq * 4 + r;
                float v = c[m][j][r] + bj[j];
                if (do_elu) v = elu_f(v);
                _Float16 h = (_Float16)v;
                int byte = ((row * 128 + col) * 2) ^ ((row & 7) << 4);
                *(_Float16*)(XH + byte) = h;
                *(_Float16*)(XL + byte) = (_Float16)(v - (float)h);
            }
        }
}

__global__ __launch_bounds__(256)
void k_node(const float* __restrict__ feat, const float* __restrict__ agg,
            const _Float16* __restrict__ wsH, const _Float16* __restrict__ wsL,
            const float* __restrict__ sb1, const float* __restrict__ sb2,
            const float* __restrict__ mb1, const float* __restrict__ mb2,
            const float* __restrict__ mb3, const float* __restrict__ mb4,
            float* __restrict__ out) {
    __shared__ _Float16 XH[64 * 128];   // 16 KB
    __shared__ _Float16 XL[64 * 128];   // 16 KB
    const int t = threadIdx.x;
    const int lane = t & 63, wv = t >> 6;
    const int colg = lane & 15, lq = lane >> 4;
    const int row0 = blockIdx.x * 64;
    f32x4 c[4][2];

    // ---- stage feat[64][64] -> X (K=64 swizzled layout) ----
    {
        int r = t >> 2, c4 = (t & 3) * 4;
        #pragma unroll
        for (int q = 0; q < 4; ++q) {
            int col = (c4 + q) * 4;
            float4 v = make_float4(0.f, 0.f, 0.f, 0.f);
            if (row0 + r < N_NODES) v = *(const float4*)&feat[(size_t)(row0 + r) * 64 + col];
            _Float16 h4h[4], h4l[4];
            float vv[4] = {v.x, v.y, v.z, v.w};
            #pragma unroll
            for (int i = 0; i < 4; ++i) {
                _Float16 h = (_Float16)vv[i];
                h4h[i] = h; h4l[i] = (_Float16)(vv[i] - (float)h);
            }
            int byte = ((r * 64 + col) * 2) ^ ((r & 7) << 4);
            *(ulong1*)((char*)XH + byte) = *(ulong1*)h4h;
            *(ulong1*)((char*)XL + byte) = *(ulong1*)h4l;
        }
    }
    __syncthreads();

    // ---- self L1: K=64, ELU ----
    mm64((const char*)XH, (const char*)XL, wsH + 0, wsL + 0, 64, lane, wv, c);
    __syncthreads();
    epi_lds((char*)XH, (char*)XL, lane, wv, c, sb1, true);
    __syncthreads();

    // ---- self L2: K=128, no ELU -> selfb stays in X ----
    mm64((const char*)XH, (const char*)XL, wsH + 8192, wsL + 8192, 128, lane, wv, c);

    // ---- stage agg -> head-L1 A-fragment registers ----
    half8 aggH[4][2], aggL[4][2];
    #pragma unroll
    for (int m = 0; m < 4; ++m) {
        int row = row0 + m * 16 + colg;
        #pragma unroll
        for (int kt = 0; kt < 2; ++kt) {
            int k0 = kt * 32 + lq * 8;
            float4 v0 = make_float4(0.f, 0.f, 0.f, 0.f), v1 = v0;
            if (row < N_NODES) {
                v0 = *(const float4*)&agg[(size_t)row * 64 + k0];
                v1 = *(const float4*)&agg[(size_t)row * 64 + k0 + 4];
            }
            float vv[8] = {v0.x, v0.y, v0.z, v0.w, v1.x, v1.y, v1.z, v1.w};
            #pragma unroll
            for (int i = 0; i < 8; ++i) {
                _Float16 h = (_Float16)vv[i];
                aggH[m][kt][i] = h;
                aggL[m][kt][i] = (_Float16)(vv[i] - (float)h);
            }
        }
    }
    __syncthreads();
    epi_lds((char*)XH, (char*)XL, lane, wv, c, sb2, false);
    __syncthreads();

    // ---- head L1: K=192 (regs + LDS), ELU ----
    mm64_h1(aggH, aggL, (const char*)XH, (const char*)XL,
            wsH + 24576, wsL + 24576, lane, wv, c);
    __syncthreads();
    epi_lds((char*)XH, (char*)XL, lane, wv, c, mb1, true);
    __syncthreads();

    // ---- head L2: K=128, ELU ----
    mm64((const char*)XH, (const char*)XL, wsH + 49152, wsL + 49152, 128, lane, wv, c);
    __syncthreads();
    epi_lds((char*)XH, (char*)XL, lane, wv, c, mb2, true);
    __syncthreads();

    // ---- head L3: K=128, ELU ----
    mm64((const char*)XH, (const char*)XL, wsH + 65536, wsL + 65536, 128, lane, wv, c);
    __syncthreads();
    epi_lds((char*)XH, (char*)XL, lane, wv, c, mb3, true);
    __syncthreads();

    // ---- head L4: K=128 -> global out ----
    mm64((const char*)XH, (const char*)XL, wsH + 81920, wsL + 81920, 128, lane, wv, c);
    {
        float bj[2] = { mb4[wv * 32 + colg], mb4[wv * 32 + 16 + colg] };
        #pragma unroll
        for (int m = 0; m < 4; ++m)
            #pragma unroll
            for (int j = 0; j < 2; ++j) {
                int col = wv * 32 + j * 16 + colg;
                #pragma unroll
                for (int r = 0; r < 4; ++r) {
                    int row = row0 + m * 16 + lq * 4 + r;
                    if (row < N_NODES)
                        out[(size_t)row * 128 + col] = c[m][j][r] + bj[j];
                }
            }
    }
}

// ============================================================================
extern "C" void kernel_launch(void* const* d_in, const int* in_sizes, int n_in,
                              void* d_out, int out_size, void* d_ws, size_t ws_size,
                              hipStream_t stream) {
    (void)in_sizes; (void)n_in; (void)out_size; (void)ws_size;
    const float* feat = (const float*)d_in[0];
    const float* off2 = (const float*)d_in[1];
    const int*   src  = (const int*)d_in[2];
    const int*   dst  = (const int*)d_in[3];
    const float* kW1  = (const float*)d_in[4];
    const float* kb1  = (const float*)d_in[5];
    const float* kW2  = (const float*)d_in[6];
    const float* kb2  = (const float*)d_in[7];
    const float* sW1  = (const float*)d_in[8];
    const float* sb1  = (const float*)d_in[9];
    const float* sW2  = (const float*)d_in[10];
    const float* sb2  = (const float*)d_in[11];
    const float* mW1  = (const float*)d_in[12];
    const float* mb1  = (const float*)d_in[13];
    const float* mW2  = (const float*)d_in[14];
    const float* mb2  = (const float*)d_in[15];
    const float* mW3  = (const float*)d_in[16];
    const float* mb3  = (const float*)d_in[17];
    const float* mW4  = (const float*)d_in[18];
    const float* mb4  = (const float*)d_in[19];

    char* ws = (char*)d_ws;
    size_t off = 0;
    auto alloc = [&](size_t bytes) -> void* {
        void* p = ws + off;
        off += (bytes + 255) & ~(size_t)255;
        return p;
    };
    int*   deg    = (int*)alloc((size_t)N_NODES * 4);
    int*   rs     = (int*)alloc((size_t)(N_NODES + 8) * 4);
    int*   cur    = (int*)alloc((size_t)N_NODES * 4);
    int*   bsum   = (int*)alloc((size_t)NB_SCAN * 4);
    int*   bpre   = (int*)alloc((size_t)NB_SCAN * 4);
    int*   eidc   = (int*)alloc((size_t)N_EDGES * 4);
    int*   srcc   = (int*)alloc((size_t)N_EDGES * 4);
    float* scorec = (float*)alloc((size_t)N_EDGES * 4);
    float* agg    = (float*)alloc((size_t)N_NODES * 64 * 4);
    _Float16* wsH = (_Float16*)alloc((size_t)WTOT * 2);
    _Float16* wsL = (_Float16*)alloc((size_t)WTOT * 2);
    _Float16* wkH = (_Float16*)alloc((size_t)KW2TOT * 2);
    _Float16* wkL = (_Float16*)alloc((size_t)KW2TOT * 2);
    _Float16* kwbuf = (_Float16*)alloc((size_t)N_EDGES * 64 * 2);

    hipMemsetAsync(deg, 0, (size_t)N_NODES * 4, stream);

    const int EB = (N_EDGES + 255) / 256;   // 3125
    const int GB = (N_NODES + 63) / 64;     // 782

    k_deg   <<<EB, 256, 0, stream>>>(dst, deg);
    k_bsum  <<<NB_SCAN, 256, 0, stream>>>(deg, bsum);
    k_bscan <<<1, 256, 0, stream>>>(bsum, bpre, rs);
    k_wr    <<<NB_SCAN, 256, 0, stream>>>(deg, bpre, rs, cur);
    k_fill  <<<EB, 256, 0, stream>>>(dst, src, off2, cur, eidc, srcc, scorec);
    k_wsplit<<<(WTOT + KW2TOT + 255) / 256, 256, 0, stream>>>(sW1, sW2, mW1, mW2, mW3, mW4,
                                                              kW2, wsH, wsL, wkH, wkL);

    k_kw <<<N_EDGES / 256, 256, 0, stream>>>(off2, eidc, kW1, kb1, wkH, wkL, kb2, kwbuf);
    k_agg<<<2048, 256, 0, stream>>>(scorec, srcc, rs, feat, kwbuf, agg);

    k_node<<<GB, 256, 0, stream>>>(feat, agg, wsH, wsL, sb1, sb2, mb1, mb2, mb3, mb4,
                                   (float*)d_out);
}

// Round 18
// 271.136 us; speedup vs baseline: 1.0404x; 1.0155x over previous
//
#include <hip/hip_runtime.h>
#include <hip/hip_bf16.h>
#include <math.h>

#define N_NODES 50000
#define N_EDGES 800000
#define NB_SCAN ((N_NODES + 255) / 256)   // 196

typedef _Float16 half8 __attribute__((ext_vector_type(8)));
typedef _Float16 half4 __attribute__((ext_vector_type(4)));
typedef float f32x4 __attribute__((ext_vector_type(4)));

// fast ELU: hardware v_exp_f32; abs err ~1e-7 << tolerance
__device__ __forceinline__ float elu_f(float x) { return x > 0.f ? x : __expf(x) - 1.f; }
__device__ __forceinline__ float edge_score(float2 o) {
    return 1.f / (fabsf(o.x) + fabsf(o.y) + 0.001f);   // > 0 always
}

// ======================= CSR build =========================================
__global__ __launch_bounds__(256)
void k_deg(const int* __restrict__ dst, int* __restrict__ deg) {
    int e = blockIdx.x * 256 + threadIdx.x;
    if (e >= N_EDGES) return;
    atomicAdd(&deg[dst[e]], 1);
}

__global__ __launch_bounds__(256)
void k_bsum(const int* __restrict__ deg, int* __restrict__ bsum) {
    int i = blockIdx.x * 256 + threadIdx.x;
    int v = (i < N_NODES) ? deg[i] : 0;
    #pragma unroll
    for (int d = 32; d; d >>= 1) v += __shfl_xor(v, d);
    __shared__ int ws[4];
    if ((threadIdx.x & 63) == 0) ws[threadIdx.x >> 6] = v;
    __syncthreads();
    if (threadIdx.x == 0) bsum[blockIdx.x] = ws[0] + ws[1] + ws[2] + ws[3];
}

__global__ __launch_bounds__(256)
void k_bscan(const int* __restrict__ bsum, int* __restrict__ bpre, int* __restrict__ rs) {
    const int t = threadIdx.x, lane = t & 63, wv = t >> 6;
    int v = (t < NB_SCAN) ? bsum[t] : 0;
    int inc = v;
    #pragma unroll
    for (int d = 1; d < 64; d <<= 1) { int u = __shfl_up(inc, d); if (lane >= d) inc += u; }
    __shared__ int wtot[4];
    if (lane == 63) wtot[wv] = inc;
    __syncthreads();
    int add = 0;
    for (int w = 0; w < wv; ++w) add += wtot[w];
    if (t < NB_SCAN) bpre[t] = inc + add - v;
    if (t == 0) rs[N_NODES] = N_EDGES;
}

__global__ __launch_bounds__(256)
void k_wr(const int* __restrict__ deg, const int* __restrict__ bpre,
          int* __restrict__ rs, int* __restrict__ cur) {
    const int i = blockIdx.x * 256 + threadIdx.x;
    const int lane = threadIdx.x & 63, wv = threadIdx.x >> 6;
    int v = (i < N_NODES) ? deg[i] : 0;
    int inc = v;
    #pragma unroll
    for (int d = 1; d < 64; d <<= 1) { int u = __shfl_up(inc, d); if (lane >= d) inc += u; }
    __shared__ int wtot[4];
    if (lane == 63) wtot[wv] = inc;
    __syncthreads();
    int add = bpre[blockIdx.x];
    for (int w = 0; w < wv; ++w) add += wtot[w];
    if (i < N_NODES) { int excl = inc - v + add; rs[i] = excl; cur[i] = excl; }
}

// CSR fill: emit eid_csr (slot -> edge), src_csr, score_csr.
__global__ __launch_bounds__(256)
void k_fill(const int* __restrict__ dst, const int* __restrict__ src,
            const float* __restrict__ off2, int* __restrict__ cur,
            int* __restrict__ eid_csr, int* __restrict__ src_csr,
            float* __restrict__ score_csr) {
    int e = blockIdx.x * 256 + threadIdx.x;
    if (e >= N_EDGES) return;
    int p = atomicAdd(&cur[dst[e]], 1);
    eid_csr[p] = e;
    src_csr[p] = src[e];
    score_csr[p] = edge_score(((const float2*)off2)[e]);
}

// ======================= weight split (node MLP + kW2) — one kernel =========
// node: L0 sW1 K=64 @0 | L1 sW2 K=128 @8192 | L2 mW1 K=192 @24576
//       L3 mW2 K=128 @49152 | L4 mW3 K=128 @65536 | L5 mW4 K=128 @81920
#define WTOT 98304
#define KW2TOT 8192
__global__ __launch_bounds__(256)
void k_wsplit(const float* __restrict__ sW1, const float* __restrict__ sW2,
              const float* __restrict__ mW1, const float* __restrict__ mW2,
              const float* __restrict__ mW3, const float* __restrict__ mW4,
              const float* __restrict__ kW2,
              _Float16* __restrict__ wsH, _Float16* __restrict__ wsL,
              _Float16* __restrict__ wkH, _Float16* __restrict__ wkL) {
    int idx = blockIdx.x * 256 + threadIdx.x;
    if (idx < WTOT) {
        const float* W; int base, K;
        if      (idx < 8192)  { W = sW1; base = 0;     K = 64;  }
        else if (idx < 24576) { W = sW2; base = 8192;  K = 128; }
        else if (idx < 49152) { W = mW1; base = 24576; K = 192; }
        else if (idx < 65536) { W = mW2; base = 49152; K = 128; }
        else if (idx < 81920) { W = mW3; base = 65536; K = 128; }
        else                  { W = mW4; base = 81920; K = 128; }
        int local = idx - base;
        int k = local >> 7, col = local & 127;
        int nt = col >> 4, colg = col & 15;
        int kt = k >> 5, lq = (k >> 3) & 3, i = k & 7;
        int fi = base + ((nt * (K >> 5) + kt) * 4 + lq) * 128 + colg * 8 + i;
        float w = W[k * 128 + col];
        _Float16 h = (_Float16)w;
        wsH[fi] = h;
        wsL[fi] = (_Float16)(w - (float)h);
    } else if (idx < WTOT + KW2TOT) {
        int x = idx - WTOT;
        int i = x & 7, colg = (x >> 3) & 15;
        int lq = (x >> 7) & 3, kt = (x >> 9) & 3, jt = x >> 11;
        int k = kt * 32 + lq * 8 + i;
        int j = jt * 16 + colg;
        float w = kW2[k * 64 + j];
        _Float16 h = (_Float16)w;
        wkH[x] = h;
        wkL[x] = (_Float16)(w - (float)h);
    }
}

// ======================= per-edge kernel-weight GEMM (CSR-ordered) ==========
// Validated form: MFMA compute + LDS-staged epilogue emitting fully-coalesced
// 16B/lane streaming stores (round-17: 82 -> 75 µs).
__global__ __launch_bounds__(256)
void k_kw(const float* __restrict__ off2, const int* __restrict__ eid_csr,
          const float* __restrict__ kW1, const float* __restrict__ kb1,
          const _Float16* __restrict__ wkH, const _Float16* __restrict__ wkL,
          const float* __restrict__ kb2, _Float16* __restrict__ kwbuf) {
    __shared__ _Float16 stg[256 * 64];   // 32 KB: 256 slots x 128 B
    const int t = threadIdx.x;
    const int lane = t & 63, wv = t >> 6;
    const int pb = blockIdx.x * 256 + wv * 64;   // CSR slot base for this wave
    const int colg = lane & 15, lq = lane >> 4;

    float2 o[4];
    #pragma unroll
    for (int et = 0; et < 4; ++et)
        o[et] = ((const float2*)off2)[eid_csr[pb + et * 16 + colg]];

    f32x4 c[4][4];   // [et][jt]
    #pragma unroll
    for (int et = 0; et < 4; ++et)
        #pragma unroll
        for (int jt = 0; jt < 4; ++jt) c[et][jt] = (f32x4){0.f, 0.f, 0.f, 0.f};

    #pragma unroll
    for (int kt = 0; kt < 4; ++kt) {
        const int k0 = kt * 32 + lq * 8;
        float4 a0 = *(const float4*)&kW1[k0];
        float4 a1 = *(const float4*)&kW1[k0 + 4];
        float4 b0 = *(const float4*)&kW1[128 + k0];
        float4 b1 = *(const float4*)&kW1[128 + k0 + 4];
        float4 c0 = *(const float4*)&kb1[k0];
        float4 c1 = *(const float4*)&kb1[k0 + 4];
        const float wa[8] = {a0.x, a0.y, a0.z, a0.w, a1.x, a1.y, a1.z, a1.w};
        const float wb[8] = {b0.x, b0.y, b0.z, b0.w, b1.x, b1.y, b1.z, b1.w};
        const float bb[8] = {c0.x, c0.y, c0.z, c0.w, c1.x, c1.y, c1.z, c1.w};

        half8 Bh[4], Bl[4];
        #pragma unroll
        for (int et = 0; et < 4; ++et) {
            #pragma unroll
            for (int i = 0; i < 8; ++i) {
                float h = elu_f(fmaf(o[et].y, wb[i], fmaf(o[et].x, wa[i], bb[i])));
                _Float16 hh = (_Float16)h;
                Bh[et][i] = hh;
                Bl[et][i] = (_Float16)(h - (float)hh);
            }
        }
        #pragma unroll
        for (int jt = 0; jt < 4; ++jt) {
            int fo = ((jt * 4 + kt) * 4 + lq) * 128 + colg * 8;
            half8 Ah = *(const half8*)&wkH[fo];
            half8 Al = *(const half8*)&wkL[fo];
            #pragma unroll
            for (int et = 0; et < 4; ++et) {
                c[et][jt] = __builtin_amdgcn_mfma_f32_16x16x32_f16(Ah, Bh[et], c[et][jt], 0, 0, 0);
                c[et][jt] = __builtin_amdgcn_mfma_f32_16x16x32_f16(Ah, Bl[et], c[et][jt], 0, 0, 0);
                c[et][jt] = __builtin_amdgcn_mfma_f32_16x16x32_f16(Al, Bh[et], c[et][jt], 0, 0, 0);
            }
        }
    }

    // ---- epilogue phase 1: D -> LDS (swizzled 8B stores) ----
    #pragma unroll
    for (int jt = 0; jt < 4; ++jt) {
        const int j0 = jt * 16 + lq * 4;
        float4 bv = *(const float4*)&kb2[j0];
        const float bias4[4] = {bv.x, bv.y, bv.z, bv.w};
        #pragma unroll
        for (int et = 0; et < 4; ++et) {
            const int ls = wv * 64 + et * 16 + colg;   // local slot 0..255
            half4 v;
            #pragma unroll
            for (int r = 0; r < 4; ++r) v[r] = (_Float16)(c[et][jt][r] + bias4[r]);
            int byte = (ls * 128 + j0 * 2) ^ ((ls & 7) << 4);
            *(half4*)((char*)stg + byte) = v;
        }
    }
    __syncthreads();

    // ---- epilogue phase 2: cooperative coalesced copy (16B/lane) ----
    const size_t gbase = (size_t)blockIdx.x * 256 * 64;
    #pragma unroll
    for (int q = 0; q < 8; ++q) {
        int byte = q * 4096 + t * 16;
        int ls = byte >> 7, off = byte & 127;
        int lb = (ls * 128 + off) ^ ((ls & 7) << 4);
        *(half8*)&kwbuf[gbase + (byte >> 1)] = *(const half8*)((const char*)stg + lb);
    }
}

// ======================= per-node softmax + gather-aggregate ================
__global__ __launch_bounds__(256)
void k_agg(const float* __restrict__ score_csr, const int* __restrict__ src_csr,
           const int* __restrict__ rs, const float* __restrict__ feat,
           const _Float16* __restrict__ kwbuf, float* __restrict__ agg) {
    const int lane = threadIdx.x & 63;
    const int wav  = threadIdx.x >> 6;
    const int gw   = blockIdx.x * 4 + wav;
    const int nw   = gridDim.x * 4;

    for (int n = gw; n < N_NODES; n += nw) {
        const int p0 = rs[n], p1 = rs[n + 1];
        if (p0 == p1) { agg[(size_t)n * 64 + lane] = 0.f; continue; }

        float mx = 0.f;
        for (int p = p0 + lane; p < p1; p += 64) mx = fmaxf(mx, score_csr[p]);
        #pragma unroll
        for (int d = 32; d; d >>= 1) mx = fmaxf(mx, __shfl_xor(mx, d));

        float sm = 0.f;
        for (int p = p0 + lane; p < p1; p += 64) sm += __expf(score_csr[p] - mx);
        #pragma unroll
        for (int d = 32; d; d >>= 1) sm += __shfl_xor(sm, d);
        const float dinv = 1.f / sm;

        float a0 = 0.f, a1 = 0.f, a2 = 0.f, a3 = 0.f;
        int p = p0;
        for (; p + 4 <= p1; p += 4) {
            float w0 = __expf(score_csr[p]     - mx) * dinv;
            float w1 = __expf(score_csr[p + 1] - mx) * dinv;
            float w2 = __expf(score_csr[p + 2] - mx) * dinv;
            float w3 = __expf(score_csr[p + 3] - mx) * dinv;
            const int s0 = src_csr[p], s1 = src_csr[p + 1];
            const int s2 = src_csr[p + 2], s3 = src_csr[p + 3];
            float f0 = feat[(size_t)s0 * 64 + lane];
            float f1 = feat[(size_t)s1 * 64 + lane];
            float f2 = feat[(size_t)s2 * 64 + lane];
            float f3 = feat[(size_t)s3 * 64 + lane];
            float k0 = (float)kwbuf[(size_t)(p)     * 64 + lane];
            float k1 = (float)kwbuf[(size_t)(p + 1) * 64 + lane];
            float k2 = (float)kwbuf[(size_t)(p + 2) * 64 + lane];
            float k3 = (float)kwbuf[(size_t)(p + 3) * 64 + lane];
            a0 = fmaf(f0 * w0, k0, a0);
            a1 = fmaf(f1 * w1, k1, a1);
            a2 = fmaf(f2 * w2, k2, a2);
            a3 = fmaf(f3 * w3, k3, a3);
        }
        for (; p < p1; ++p) {
            float wgt = __expf(score_csr[p] - mx) * dinv;
            float f = feat[(size_t)src_csr[p] * 64 + lane];
            float kv = (float)kwbuf[(size_t)p * 64 + lane];
            a0 = fmaf(f * wgt, kv, a0);
        }
        agg[(size_t)n * 64 + lane] = (a0 + a1) + (a2 + a3);
    }
}

// ======================= fused node pipeline (MFMA) =========================
// X LDS is 64x128 hi/lo (32 KB total, single buffer). agg for head-L1 staged
// in registers. Final output staged in (reused) LDS -> coalesced f32x4 stores.
__device__ __forceinline__
void mm64(const char* XH, const char* XL, const _Float16* __restrict__ WH,
          const _Float16* __restrict__ WL, int K, int lane, int wv, f32x4 c[4][2]) {
    const int colg = lane & 15, lq = lane >> 4;
    #pragma unroll
    for (int m = 0; m < 4; ++m)
        #pragma unroll
        for (int j = 0; j < 2; ++j) c[m][j] = (f32x4){0.f, 0.f, 0.f, 0.f};
    const int KT = K >> 5;
    for (int kt = 0; kt < KT; ++kt) {
        half8 Bh[2], Bl[2], Ah[4], Al[4];
        #pragma unroll
        for (int j = 0; j < 2; ++j) {
            int fo = ((((wv * 2 + j) * KT + kt) * 4 + lq) * 128) + colg * 8;
            Bh[j] = *(const half8*)&WH[fo];
            Bl[j] = *(const half8*)&WL[fo];
        }
        #pragma unroll
        for (int m = 0; m < 4; ++m) {
            int row = m * 16 + colg;
            int byte = ((row * K + kt * 32 + lq * 8) * 2) ^ ((row & 7) << 4);
            Ah[m] = *(const half8*)(XH + byte);
            Al[m] = *(const half8*)(XL + byte);
        }
        #pragma unroll
        for (int m = 0; m < 4; ++m)
            #pragma unroll
            for (int j = 0; j < 2; ++j) {
                c[m][j] = __builtin_amdgcn_mfma_f32_16x16x32_f16(Ah[m], Bh[j], c[m][j], 0, 0, 0);
                c[m][j] = __builtin_amdgcn_mfma_f32_16x16x32_f16(Ah[m], Bl[j], c[m][j], 0, 0, 0);
                c[m][j] = __builtin_amdgcn_mfma_f32_16x16x32_f16(Al[m], Bh[j], c[m][j], 0, 0, 0);
            }
    }
}

// head-L1: K=192; kt 0,1 (agg) from registers, kt 2..5 (selfb) from LDS.
__device__ __forceinline__
void mm64_h1(const half8 aggH[4][2], const half8 aggL[4][2],
             const char* XH, const char* XL,
             const _Float16* __restrict__ WH, const _Float16* __restrict__ WL,
             int lane, int wv, f32x4 c[4][2]) {
    const int colg = lane & 15, lq = lane >> 4;
    #pragma unroll
    for (int m = 0; m < 4; ++m)
        #pragma unroll
        for (int j = 0; j < 2; ++j) c[m][j] = (f32x4){0.f, 0.f, 0.f, 0.f};
    #pragma unroll
    for (int kt = 0; kt < 6; ++kt) {
        half8 Bh[2], Bl[2], Ah[4], Al[4];
        #pragma unroll
        for (int j = 0; j < 2; ++j) {
            int fo = ((((wv * 2 + j) * 6 + kt) * 4 + lq) * 128) + colg * 8;
            Bh[j] = *(const half8*)&WH[fo];
            Bl[j] = *(const half8*)&WL[fo];
        }
        if (kt < 2) {
            #pragma unroll
            for (int m = 0; m < 4; ++m) { Ah[m] = aggH[m][kt]; Al[m] = aggL[m][kt]; }
        } else {
            #pragma unroll
            for (int m = 0; m < 4; ++m) {
                int row = m * 16 + colg;
                int byte = ((row * 128 + (kt - 2) * 32 + lq * 8) * 2) ^ ((row & 7) << 4);
                Ah[m] = *(const half8*)(XH + byte);
                Al[m] = *(const half8*)(XL + byte);
            }
        }
        #pragma unroll
        for (int m = 0; m < 4; ++m)
            #pragma unroll
            for (int j = 0; j < 2; ++j) {
                c[m][j] = __builtin_amdgcn_mfma_f32_16x16x32_f16(Ah[m], Bh[j], c[m][j], 0, 0, 0);
                c[m][j] = __builtin_amdgcn_mfma_f32_16x16x32_f16(Ah[m], Bl[j], c[m][j], 0, 0, 0);
                c[m][j] = __builtin_amdgcn_mfma_f32_16x16x32_f16(Al[m], Bh[j], c[m][j], 0, 0, 0);
            }
    }
}

__device__ __forceinline__
void epi_lds(char* XH, char* XL, int lane, int wv,
             f32x4 c[4][2], const float* __restrict__ bias, bool do_elu) {
    const int colg = lane & 15, lq = lane >> 4;
    float bj[2] = { bias[wv * 32 + colg], bias[wv * 32 + 16 + colg] };
    #pragma unroll
    for (int m = 0; m < 4; ++m)
        #pragma unroll
        for (int j = 0; j < 2; ++j) {
            int col = wv * 32 + j * 16 + colg;
            #pragma unroll
            for (int r = 0; r < 4; ++r) {
                int row = m * 16 + lq * 4 + r;
                float v = c[m][j][r] + bj[j];
                if (do_elu) v = elu_f(v);
                _Float16 h = (_Float16)v;
                int byte = ((row * 128 + col) * 2) ^ ((row & 7) << 4);
                *(_Float16*)(XH + byte) = h;
                *(_Float16*)(XL + byte) = (_Float16)(v - (float)h);
            }
        }
}

__global__ __launch_bounds__(256)
void k_node(const float* __restrict__ feat, const float* __restrict__ agg,
            const _Float16* __restrict__ wsH, const _Float16* __restrict__ wsL,
            const float* __restrict__ sb1, const float* __restrict__ sb2,
            const float* __restrict__ mb1, const float* __restrict__ mb2,
            const float* __restrict__ mb3, const float* __restrict__ mb4,
            float* __restrict__ out) {
    __shared__ __align__(16) char smem[32768];   // XH (16K) | XL (16K); reused for out
    char* XH = smem;
    char* XL = smem + 16384;
    const int t = threadIdx.x;
    const int lane = t & 63, wv = t >> 6;
    const int colg = lane & 15, lq = lane >> 4;
    const int row0 = blockIdx.x * 64;
    f32x4 c[4][2];

    // ---- stage feat[64][64] -> X (K=64 swizzled layout) ----
    {
        int r = t >> 2, c4 = (t & 3) * 4;
        #pragma unroll
        for (int q = 0; q < 4; ++q) {
            int col = (c4 + q) * 4;
            float4 v = make_float4(0.f, 0.f, 0.f, 0.f);
            if (row0 + r < N_NODES) v = *(const float4*)&feat[(size_t)(row0 + r) * 64 + col];
            _Float16 h4h[4], h4l[4];
            float vv[4] = {v.x, v.y, v.z, v.w};
            #pragma unroll
            for (int i = 0; i < 4; ++i) {
                _Float16 h = (_Float16)vv[i];
                h4h[i] = h; h4l[i] = (_Float16)(vv[i] - (float)h);
            }
            int byte = ((r * 64 + col) * 2) ^ ((r & 7) << 4);
            *(ulong1*)(XH + byte) = *(ulong1*)h4h;
            *(ulong1*)(XL + byte) = *(ulong1*)h4l;
        }
    }
    __syncthreads();

    // ---- self L1: K=64, ELU ----
    mm64(XH, XL, wsH + 0, wsL + 0, 64, lane, wv, c);
    __syncthreads();
    epi_lds(XH, XL, lane, wv, c, sb1, true);
    __syncthreads();

    // ---- self L2: K=128, no ELU -> selfb stays in X ----
    mm64(XH, XL, wsH + 8192, wsL + 8192, 128, lane, wv, c);

    // ---- stage agg -> head-L1 A-fragment registers ----
    half8 aggH[4][2], aggL[4][2];
    #pragma unroll
    for (int m = 0; m < 4; ++m) {
        int row = row0 + m * 16 + colg;
        #pragma unroll
        for (int kt = 0; kt < 2; ++kt) {
            int k0 = kt * 32 + lq * 8;
            float4 v0 = make_float4(0.f, 0.f, 0.f, 0.f), v1 = v0;
            if (row < N_NODES) {
                v0 = *(const float4*)&agg[(size_t)row * 64 + k0];
                v1 = *(const float4*)&agg[(size_t)row * 64 + k0 + 4];
            }
            float vv[8] = {v0.x, v0.y, v0.z, v0.w, v1.x, v1.y, v1.z, v1.w};
            #pragma unroll
            for (int i = 0; i < 8; ++i) {
                _Float16 h = (_Float16)vv[i];
                aggH[m][kt][i] = h;
                aggL[m][kt][i] = (_Float16)(vv[i] - (float)h);
            }
        }
    }
    __syncthreads();
    epi_lds(XH, XL, lane, wv, c, sb2, false);
    __syncthreads();

    // ---- head L1: K=192 (regs + LDS), ELU ----
    mm64_h1(aggH, aggL, XH, XL, wsH + 24576, wsL + 24576, lane, wv, c);
    __syncthreads();
    epi_lds(XH, XL, lane, wv, c, mb1, true);
    __syncthreads();

    // ---- head L2: K=128, ELU ----
    mm64(XH, XL, wsH + 49152, wsL + 49152, 128, lane, wv, c);
    __syncthreads();
    epi_lds(XH, XL, lane, wv, c, mb2, true);
    __syncthreads();

    // ---- head L3: K=128, ELU ----
    mm64(XH, XL, wsH + 65536, wsL + 65536, 128, lane, wv, c);
    __syncthreads();
    epi_lds(XH, XL, lane, wv, c, mb3, true);
    __syncthreads();

    // ---- head L4: K=128 -> stage f32 out in LDS, then coalesced stores ----
    mm64(XH, XL, wsH + 81920, wsL + 81920, 128, lane, wv, c);
    __syncthreads();   // all waves done reading X before overwrite
    {
        float* os = (float*)smem;   // [64][128] f32 = 32 KB
        float bj[2] = { mb4[wv * 32 + colg], mb4[wv * 32 + 16 + colg] };
        #pragma unroll
        for (int m = 0; m < 4; ++m)
            #pragma unroll
            for (int j = 0; j < 2; ++j) {
                int col = wv * 32 + j * 16 + colg;
                #pragma unroll
                for (int r = 0; r < 4; ++r) {
                    int row = m * 16 + lq * 4 + r;
                    os[row * 128 + col] = c[m][j][r] + bj[j];
                }
            }
    }
    __syncthreads();
    {
        const float* os = (const float*)smem;
        const int rows = (N_NODES - row0 < 64) ? (N_NODES - row0) : 64;
        const int nfl = rows * 128;
        const size_t gb = (size_t)row0 * 128;
        #pragma unroll
        for (int q = 0; q < 8; ++q) {
            int idx = q * 1024 + t * 4;
            if (idx < nfl)
                *(float4*)&out[gb + idx] = *(const float4*)&os[idx];
        }
    }
}

// ============================================================================
extern "C" void kernel_launch(void* const* d_in, const int* in_sizes, int n_in,
                              void* d_out, int out_size, void* d_ws, size_t ws_size,
                              hipStream_t stream) {
    (void)in_sizes; (void)n_in; (void)out_size; (void)ws_size;
    const float* feat = (const float*)d_in[0];
    const float* off2 = (const float*)d_in[1];
    const int*   src  = (const int*)d_in[2];
    const int*   dst  = (const int*)d_in[3];
    const float* kW1  = (const float*)d_in[4];
    const float* kb1  = (const float*)d_in[5];
    const float* kW2  = (const float*)d_in[6];
    const float* kb2  = (const float*)d_in[7];
    const float* sW1  = (const float*)d_in[8];
    const float* sb1  = (const float*)d_in[9];
    const float* sW2  = (const float*)d_in[10];
    const float* sb2  = (const float*)d_in[11];
    const float* mW1  = (const float*)d_in[12];
    const float* mb1  = (const float*)d_in[13];
    const float* mW2  = (const float*)d_in[14];
    const float* mb2  = (const float*)d_in[15];
    const float* mW3  = (const float*)d_in[16];
    const float* mb3  = (const float*)d_in[17];
    const float* mW4  = (const float*)d_in[18];
    const float* mb4  = (const float*)d_in[19];

    char* ws = (char*)d_ws;
    size_t off = 0;
    auto alloc = [&](size_t bytes) -> void* {
        void* p = ws + off;
        off += (bytes + 255) & ~(size_t)255;
        return p;
    };
    int*   deg    = (int*)alloc((size_t)N_NODES * 4);
    int*   rs     = (int*)alloc((size_t)(N_NODES + 8) * 4);
    int*   cur    = (int*)alloc((size_t)N_NODES * 4);
    int*   bsum   = (int*)alloc((size_t)NB_SCAN * 4);
    int*   bpre   = (int*)alloc((size_t)NB_SCAN * 4);
    int*   eidc   = (int*)alloc((size_t)N_EDGES * 4);
    int*   srcc   = (int*)alloc((size_t)N_EDGES * 4);
    float* scorec = (float*)alloc((size_t)N_EDGES * 4);
    float* agg    = (float*)alloc((size_t)N_NODES * 64 * 4);
    _Float16* wsH = (_Float16*)alloc((size_t)WTOT * 2);
    _Float16* wsL = (_Float16*)alloc((size_t)WTOT * 2);
    _Float16* wkH = (_Float16*)alloc((size_t)KW2TOT * 2);
    _Float16* wkL = (_Float16*)alloc((size_t)KW2TOT * 2);
    _Float16* kwbuf = (_Float16*)alloc((size_t)N_EDGES * 64 * 2);

    hipMemsetAsync(deg, 0, (size_t)N_NODES * 4, stream);

    const int EB = (N_EDGES + 255) / 256;   // 3125
    const int GB = (N_NODES + 63) / 64;     // 782

    k_deg   <<<EB, 256, 0, stream>>>(dst, deg);
    k_bsum  <<<NB_SCAN, 256, 0, stream>>>(deg, bsum);
    k_bscan <<<1, 256, 0, stream>>>(bsum, bpre, rs);
    k_wr    <<<NB_SCAN, 256, 0, stream>>>(deg, bpre, rs, cur);
    k_fill  <<<EB, 256, 0, stream>>>(dst, src, off2, cur, eidc, srcc, scorec);
    k_wsplit<<<(WTOT + KW2TOT + 255) / 256, 256, 0, stream>>>(sW1, sW2, mW1, mW2, mW3, mW4,
                                                              kW2, wsH, wsL, wkH, wkL);

    k_kw <<<N_EDGES / 256, 256, 0, stream>>>(off2, eidc, kW1, kb1, wkH, wkL, kb2, kwbuf);
    k_agg<<<2048, 256, 0, stream>>>(scorec, srcc, rs, feat, kwbuf, agg);

    k_node<<<GB, 256, 0, stream>>>(feat, agg, wsH, wsL, sb1, sb2, mb1, mb2, mb3, mb4,
                                   (float*)d_out);
}